// Round 1
// baseline (306.740 us; speedup 1.0000x reference)
//
#include <hip/hip_runtime.h>

// SSIM fused kernel for B=64, C=1, H=W=512 fp32.
// Separable 11x11 Gaussian (window is outer product of symmetric 1D g;
// g[i] recovered exactly as row-sum of the 2D window since sum(g)==1).

#define IMG 512
#define TW 32
#define TH 32
#define HALO 5
#define IW (TW + 2*HALO)   // 42
#define IH (TH + 2*HALO)   // 42
#define NIN (IH*IW)        // 1764
#define NH  (IH*TW)        // 1344

__global__ __launch_bounds__(256) void ssim_tile(
    const float* __restrict__ x, const float* __restrict__ y,
    const float* __restrict__ win, float* __restrict__ partial)
{
    __shared__ float sx[NIN];
    __shared__ float sy[NIN];
    __shared__ float h0[NH], h1[NH], h2[NH], h3[NH], h4[NH];
    __shared__ float g[16];
    __shared__ float redbuf[4];

    const int tid = threadIdx.x;

    // 1D kernel from row sums of the 2D window (exact: rows of w2d sum to g[i])
    if (tid < 11) {
        float s = 0.f;
        #pragma unroll
        for (int j = 0; j < 11; ++j) s += win[tid*11 + j];
        g[tid] = s;
    }

    const int x0 = blockIdx.x * TW;
    const int y0 = blockIdx.y * TH;
    const float* xb = x + (size_t)blockIdx.z * (IMG*IMG);
    const float* yb = y + (size_t)blockIdx.z * (IMG*IMG);

    // Stage x,y tile with halo, zero-padded at image borders.
    for (int idx = tid; idx < NIN; idx += 256) {
        int r = idx / IW;
        int c = idx - r*IW;
        int gy = y0 + r - HALO;
        int gx = x0 + c - HALO;
        float vx = 0.f, vy = 0.f;
        if (gy >= 0 && gy < IMG && gx >= 0 && gx < IMG) {
            int o = gy*IMG + gx;
            vx = xb[o];
            vy = yb[o];
        }
        sx[idx] = vx;
        sy[idx] = vy;
    }
    __syncthreads();

    // Horizontal separable pass: 5 channels (x, y, xx, yy, xy).
    // Uses symmetric-pair trick: g[u] == g[10-u] bitwise.
    for (int idx = tid; idx < NH; idx += 256) {
        int r = idx / TW;
        int c = idx - r*TW;
        const float* px = &sx[r*IW + c];
        const float* py = &sy[r*IW + c];
        float ax = 0.f, ay = 0.f, axx = 0.f, ayy = 0.f, axy = 0.f;
        #pragma unroll
        for (int u = 0; u < 5; ++u) {
            float w  = g[u];
            float xa = px[u],    xc = px[10-u];
            float ya = py[u],    yc = py[10-u];
            ax  += w * (xa + xc);
            ay  += w * (ya + yc);
            axx += w * (xa*xa + xc*xc);
            ayy += w * (ya*ya + yc*yc);
            axy += w * (xa*ya + xc*yc);
        }
        float w5 = g[5];
        float xm = px[5], ym = py[5];
        ax  += w5 * xm;
        ay  += w5 * ym;
        axx += w5 * xm*xm;
        ayy += w5 * ym*ym;
        axy += w5 * xm*ym;
        h0[idx] = ax; h1[idx] = ay; h2[idx] = axx; h3[idx] = ayy; h4[idx] = axy;
    }
    __syncthreads();

    // Vertical pass + SSIM map + per-thread accumulation.
    const float C1 = 1.0e-4f;  // (0.01*1.0)^2
    const float C2 = 9.0e-4f;  // (0.03*1.0)^2
    float acc = 0.f;
    for (int idx = tid; idx < TH*TW; idx += 256) {
        int r = idx / TW;
        int c = idx - r*TW;
        float mx = 0.f, my = 0.f, exx = 0.f, eyy = 0.f, exy = 0.f;
        #pragma unroll
        for (int u = 0; u < 5; ++u) {
            float w = g[u];
            int o1 = (r+u)*TW + c;
            int o2 = (r+10-u)*TW + c;
            mx  += w * (h0[o1] + h0[o2]);
            my  += w * (h1[o1] + h1[o2]);
            exx += w * (h2[o1] + h2[o2]);
            eyy += w * (h3[o1] + h3[o2]);
            exy += w * (h4[o1] + h4[o2]);
        }
        float w5 = g[5];
        int oc = (r+5)*TW + c;
        mx  += w5 * h0[oc];
        my  += w5 * h1[oc];
        exx += w5 * h2[oc];
        eyy += w5 * h3[oc];
        exy += w5 * h4[oc];

        float mxx = mx*mx, myy = my*my, mxy = mx*my;
        float sxx = exx - mxx;
        float syy = eyy - myy;
        float sxy = exy - mxy;
        float num = (2.f*mxy + C1) * (2.f*sxy + C2);
        float den = (mxx + myy + C1) * (sxx + syy + C2);
        acc += num / den;
    }

    // Block reduction: wave shuffle then LDS.
    #pragma unroll
    for (int off = 32; off > 0; off >>= 1) acc += __shfl_down(acc, off, 64);
    int wid = tid >> 6, lane = tid & 63;
    if (lane == 0) redbuf[wid] = acc;
    __syncthreads();
    if (tid == 0) {
        float s = redbuf[0] + redbuf[1] + redbuf[2] + redbuf[3];
        partial[((size_t)blockIdx.z * gridDim.y + blockIdx.y) * gridDim.x + blockIdx.x] = s;
    }
}

__global__ __launch_bounds__(256) void ssim_finalize(
    const float* __restrict__ partial, int n, float* __restrict__ out)
{
    __shared__ double red[4];
    double acc = 0.0;
    for (int i = threadIdx.x; i < n; i += 256) acc += (double)partial[i];
    #pragma unroll
    for (int off = 32; off > 0; off >>= 1) acc += __shfl_down(acc, off, 64);
    int wid = threadIdx.x >> 6, lane = threadIdx.x & 63;
    if (lane == 0) red[wid] = acc;
    __syncthreads();
    if (threadIdx.x == 0) {
        double s = red[0] + red[1] + red[2] + red[3];
        out[0] = (float)(s / (64.0 * 512.0 * 512.0));
    }
}

extern "C" void kernel_launch(void* const* d_in, const int* in_sizes, int n_in,
                              void* d_out, int out_size, void* d_ws, size_t ws_size,
                              hipStream_t stream) {
    (void)in_sizes; (void)n_in; (void)out_size; (void)ws_size;
    const float* x   = (const float*)d_in[0];
    const float* y   = (const float*)d_in[1];
    const float* win = (const float*)d_in[2];
    float* out = (float*)d_out;
    float* partial = (float*)d_ws;   // 16384 floats = 64 KB scratch

    dim3 grid(IMG/TW, IMG/TH, 64);   // 16 x 16 x 64 = 16384 blocks
    ssim_tile<<<grid, 256, 0, stream>>>(x, y, win, partial);
    ssim_finalize<<<1, 256, 0, stream>>>(partial, 16384, out);
}

// Round 2
// 235.898 us; speedup vs baseline: 1.3003x; 1.3003x over previous
//
#include <hip/hip_runtime.h>

// Fused SSIM, B=64, C=1, 512x512 fp32, 11x11 Gaussian (separable).
// Phase 1: vertical conv from GLOBAL via register sliding strip (no input LDS).
// Phase 2: horizontal conv from LDS via vectorized float4 reads + SSIM + reduce.

#define IMG 512
#define TW 64            // output tile width
#define TH 32            // output tile height
#define PADW 80          // v-result columns: output cols -8..71 (16B-aligned halo)
#define VSTRIDE 84       // LDS row stride in floats (336B, 16B-aligned, breaks 16-way conflicts)
#define NSEG 4
#define SEGROWS 8        // output rows per phase-1 segment
#define INROWS 18        // input rows per segment (8 + 10 halo)
#define NTHREADS 320

__global__ __launch_bounds__(NTHREADS, 4) void ssim_fused(
    const float* __restrict__ x, const float* __restrict__ y,
    const float* __restrict__ win, float* __restrict__ partial)
{
    __shared__ __align__(16) float v[5][TH][VSTRIDE];   // 53760 B
    __shared__ float sg[11];
    __shared__ float redbuf[5];

    const int tid = threadIdx.x;

    // 1D kernel g[i] = row sums of the 2D window (exact since sum(g)==1).
    if (tid < 11) {
        float s = 0.f;
        #pragma unroll
        for (int j = 0; j < 11; ++j) s += win[tid * 11 + j];
        sg[tid] = s;
    }

    const int x0 = blockIdx.x * TW;
    const int y0 = blockIdx.y * TH;
    const size_t img_off = (size_t)blockIdx.z * (IMG * IMG);
    const float* __restrict__ xb = x + img_off;
    const float* __restrict__ yb = y + img_off;

    // ---------------- Phase 1: vertical conv (global -> LDS) ----------------
    const int c  = tid % PADW;        // LDS column 0..79
    const int s  = tid / PADW;        // segment 0..3
    const int r0 = s * SEGROWS;       // first output row of this segment
    const int gx = x0 + c - 8;        // global column
    const bool cok = (gx >= 0) && (gx < IMG);

    float vx[INROWS], vy[INROWS];
    #pragma unroll
    for (int j = 0; j < INROWS; ++j) {
        int gy = y0 + r0 - 5 + j;
        bool ok = cok && (gy >= 0) && (gy < IMG);
        int o = ok ? (gy * IMG + gx) : 0;
        float a = xb[o];
        float b = yb[o];
        vx[j] = ok ? a : 0.f;
        vy[j] = ok ? b : 0.f;
    }

    __syncthreads();   // sg visible
    float gk[11];
    #pragma unroll
    for (int k = 0; k < 11; ++k) gk[k] = sg[k];

    // channel 0: x, channel 1: y
    {
        #pragma unroll
        for (int i = 0; i < SEGROWS; ++i) {
            float a = 0.f, b = 0.f;
            #pragma unroll
            for (int k = 0; k < 11; ++k) { a += gk[k] * vx[i + k]; b += gk[k] * vy[i + k]; }
            v[0][r0 + i][c] = a;
            v[1][r0 + i][c] = b;
        }
    }
    // channel 2: x*x
    {
        float t[INROWS];
        #pragma unroll
        for (int j = 0; j < INROWS; ++j) t[j] = vx[j] * vx[j];
        #pragma unroll
        for (int i = 0; i < SEGROWS; ++i) {
            float a = 0.f;
            #pragma unroll
            for (int k = 0; k < 11; ++k) a += gk[k] * t[i + k];
            v[2][r0 + i][c] = a;
        }
    }
    // channel 3: y*y
    {
        float t[INROWS];
        #pragma unroll
        for (int j = 0; j < INROWS; ++j) t[j] = vy[j] * vy[j];
        #pragma unroll
        for (int i = 0; i < SEGROWS; ++i) {
            float a = 0.f;
            #pragma unroll
            for (int k = 0; k < 11; ++k) a += gk[k] * t[i + k];
            v[3][r0 + i][c] = a;
        }
    }
    // channel 4: x*y
    {
        float t[INROWS];
        #pragma unroll
        for (int j = 0; j < INROWS; ++j) t[j] = vx[j] * vy[j];
        #pragma unroll
        for (int i = 0; i < SEGROWS; ++i) {
            float a = 0.f;
            #pragma unroll
            for (int k = 0; k < 11; ++k) a += gk[k] * t[i + k];
            v[4][r0 + i][c] = a;
        }
    }

    __syncthreads();

    // ---------------- Phase 2: horizontal conv + SSIM ----------------
    const float C1 = 1.0e-4f;
    const float C2 = 9.0e-4f;
    float acc = 0.f;

    if (tid < 256) {
        const int rr = tid >> 3;          // row 0..31
        const int c0 = (tid & 7) * 8;     // output col base 0..56 (step 8)

        float mx[8], my[8], exx[8], eyy[8], exy[8];

        #pragma unroll
        for (int ch = 0; ch < 5; ++ch) {
            float t[24];
            const float4* vp = (const float4*)&v[ch][rr][c0];
            #pragma unroll
            for (int q = 0; q < 6; ++q) {
                float4 f = vp[q];
                t[4*q + 0] = f.x; t[4*q + 1] = f.y; t[4*q + 2] = f.z; t[4*q + 3] = f.w;
            }
            #pragma unroll
            for (int i = 0; i < 8; ++i) {
                float a = 0.f;
                #pragma unroll
                for (int k = 0; k < 11; ++k) a += gk[k] * t[3 + i + k];
                if (ch == 0) mx[i] = a;
                else if (ch == 1) my[i] = a;
                else if (ch == 2) exx[i] = a;
                else if (ch == 3) eyy[i] = a;
                else exy[i] = a;
            }
        }

        #pragma unroll
        for (int i = 0; i < 8; ++i) {
            float mxv = mx[i], myv = my[i];
            float mxx = mxv * mxv, myy = myv * myv, mxy = mxv * myv;
            float sxx = exx[i] - mxx;
            float syy = eyy[i] - myy;
            float sxy = exy[i] - mxy;
            float num = (2.f * mxy + C1) * (2.f * sxy + C2);
            float den = (mxx + myy + C1) * (sxx + syy + C2);
            acc += num * __builtin_amdgcn_rcpf(den);
        }
    }

    // ---------------- Phase 3: block reduction ----------------
    #pragma unroll
    for (int off = 32; off > 0; off >>= 1) acc += __shfl_down(acc, off, 64);
    int wid = tid >> 6, lane = tid & 63;
    if (lane == 0) redbuf[wid] = acc;
    __syncthreads();
    if (tid == 0) {
        float ssum = redbuf[0] + redbuf[1] + redbuf[2] + redbuf[3] + redbuf[4];
        partial[((size_t)blockIdx.z * gridDim.y + blockIdx.y) * gridDim.x + blockIdx.x] = ssum;
    }
}

__global__ __launch_bounds__(256) void ssim_finalize(
    const float* __restrict__ partial, int n, float* __restrict__ out)
{
    __shared__ double red[4];
    double acc = 0.0;
    for (int i = threadIdx.x; i < n; i += 256) acc += (double)partial[i];
    #pragma unroll
    for (int off = 32; off > 0; off >>= 1) acc += __shfl_down(acc, off, 64);
    int wid = threadIdx.x >> 6, lane = threadIdx.x & 63;
    if (lane == 0) red[wid] = acc;
    __syncthreads();
    if (threadIdx.x == 0) {
        double s = red[0] + red[1] + red[2] + red[3];
        out[0] = (float)(s / (64.0 * 512.0 * 512.0));
    }
}

extern "C" void kernel_launch(void* const* d_in, const int* in_sizes, int n_in,
                              void* d_out, int out_size, void* d_ws, size_t ws_size,
                              hipStream_t stream) {
    (void)in_sizes; (void)n_in; (void)out_size; (void)ws_size;
    const float* x   = (const float*)d_in[0];
    const float* y   = (const float*)d_in[1];
    const float* win = (const float*)d_in[2];
    float* out = (float*)d_out;
    float* partial = (float*)d_ws;     // 8192 floats = 32 KB

    dim3 grid(IMG / TW, IMG / TH, 64); // 8 x 16 x 64 = 8192 blocks
    ssim_fused<<<grid, NTHREADS, 0, stream>>>(x, y, win, partial);
    ssim_finalize<<<1, 256, 0, stream>>>(partial, 8192, out);
}